// Round 10
// baseline (1114.342 us; speedup 1.0000x reference)
//
#include <hip/hip_runtime.h>

#define B_   8
#define D_   256
#define T_   4096
#define Q_   8
#define K_   1024
#define BT_  (B_*T_)            // 32768 rows
#define N_   (B_*T_*D_)         // 8388608 elements
#define LOSS_OFF N_
#define IDX_OFF  (N_+1)
#define ROWS 32                 // rows per block

typedef __attribute__((ext_vector_type(8))) short short8;
typedef __attribute__((ext_vector_type(4))) float float4v;

union U4S8 { uint4 u; short8 s; };

__device__ __forceinline__ unsigned short f2bf(float x) {
    unsigned int u = __float_as_uint(x);
    unsigned int r = (u + 0x7FFFu + ((u >> 16) & 1u)) >> 16;
    return (unsigned short)r;
}
__device__ __forceinline__ float bf2f(unsigned short b) {
    return __uint_as_float(((unsigned int)b) << 16);
}
// order-preserving float<->uint key (exact min via integer atomicMin)
__device__ __forceinline__ unsigned fkey(float f) {
    unsigned u = __float_as_uint(f);
    return (u & 0x80000000u) ? ~u : (u | 0x80000000u);
}
__device__ __forceinline__ float fkeyinv(unsigned k) {
    unsigned u = (k & 0x80000000u) ? (k & 0x7fffffffu) : ~k;
    return __uint_as_float(u);
}

// ---------------- init: z [B,D,T] -> residual [B,T,D], tiled transpose ----------------

__global__ void k_init(const float* __restrict__ z, float* __restrict__ residual,
                       double* lossAcc, unsigned* MelU) {
    __shared__ float tile[32][33];
    int b  = blockIdx.z;
    int d0 = blockIdx.y * 32;
    int t0 = blockIdx.x * 32;
    int tx = threadIdx.x & 31;
    int ty = threadIdx.x >> 5;
    const float* zb = z + (size_t)b * D_ * T_;
    #pragma unroll
    for (int r = 0; r < 32; r += 8)
        tile[ty + r][tx] = zb[(size_t)(d0 + ty + r) * T_ + t0 + tx];
    __syncthreads();
    float* rb = residual + (size_t)b * T_ * D_;
    #pragma unroll
    for (int r = 0; r < 32; r += 8)
        rb[(size_t)(t0 + ty + r) * D_ + d0 + tx] = tile[tx][ty + r];
    if (b == 0 && blockIdx.x == 0 && blockIdx.y == 0 && threadIdx.x == 0) {
        *lossAcc = 0.0;
        #pragma unroll
        for (int i = 0; i < Q_; ++i) MelU[i] = 0u;
    }
}

// ---------------- B-fragment precompute: cb -> bf16 hi/lo in MFMA lane layout ----------
// Layout: Bfrag[((q*64 + ct)*8 + kc)*2*64 + part*64 + lane] : uint4 (8 bf16)
// lane supplies B[k = kc*32 + (lane>>4)*8 + j][n = ct*16 + (lane&15)], j=0..7
// (lo part still written but no longer read by k_stagepair -- hi-only filter.)

__global__ void k_bfrag(const float* __restrict__ cb, uint4* __restrict__ Bfrag) {
    int gid = blockIdx.x * 256 + threadIdx.x;      // 262144 total
    int q    = gid >> 15;
    int rem  = gid & 32767;
    int ct   = rem >> 9;
    int kc   = (rem >> 6) & 7;
    int lane = rem & 63;
    int cand = ct * 16 + (lane & 15);
    int kb   = kc * 32 + (lane >> 4) * 8;
    const float* e = cb + ((size_t)q * K_ + cand) * D_ + kb;
    float4v u0 = *(const float4v*)(e);
    float4v u1 = *(const float4v*)(e + 4);
    float vv[8] = {u0.x, u0.y, u0.z, u0.w, u1.x, u1.y, u1.z, u1.w};
    unsigned short h[8], l[8];
    #pragma unroll
    for (int j = 0; j < 8; ++j) {
        float v = vv[j];
        h[j] = f2bf(v);
        l[j] = f2bf(v - bf2f(h[j]));
    }
    uint4 hi, lo;
    hi.x = (unsigned)h[0] | ((unsigned)h[1] << 16);
    hi.y = (unsigned)h[2] | ((unsigned)h[3] << 16);
    hi.z = (unsigned)h[4] | ((unsigned)h[5] << 16);
    hi.w = (unsigned)h[6] | ((unsigned)h[7] << 16);
    lo.x = (unsigned)l[0] | ((unsigned)l[1] << 16);
    lo.y = (unsigned)l[2] | ((unsigned)l[3] << 16);
    lo.z = (unsigned)l[4] | ((unsigned)l[5] << 16);
    lo.w = (unsigned)l[6] | ((unsigned)l[7] << 16);
    size_t base = (((size_t)(q * 64 + ct) * 8 + kc) * 2) * 64;
    Bfrag[base + lane]      = hi;
    Bfrag[base + 64 + lane] = lo;
}

// ---------------- S_e (fp64 sum of fl32(e^2)) + per-stage max bf16-residual norm ------

__global__ void k_se(const float* __restrict__ cb, float* __restrict__ Se,
                     unsigned* __restrict__ MelU) {
    int gid = blockIdx.x * 256 + threadIdx.x;      // Q*K*16 = 131072 threads
    int i  = gid >> 4;
    int ln = gid & 15;
    if (i >= Q_ * K_) return;
    const float* e = cb + (size_t)i * D_ + ln * 16;
    float4v v0 = *(const float4v*)(e);
    float4v v1 = *(const float4v*)(e + 4);
    float4v v2 = *(const float4v*)(e + 8);
    float4v v3 = *(const float4v*)(e + 12);
    float vv[16] = {v0.x, v0.y, v0.z, v0.w, v1.x, v1.y, v1.z, v1.w,
                    v2.x, v2.y, v2.z, v2.w, v3.x, v3.y, v3.z, v3.w};
    double s = 0.0, s2 = 0.0;
    #pragma unroll
    for (int d = 0; d < 16; ++d) {
        float v = vv[d];
        float a = v * v;
        s += (double)a;
        float el = v - bf2f(f2bf(v));
        s2 += (double)(el * el);
    }
    #pragma unroll
    for (int st = 8; st > 0; st >>= 1) {
        s  += __shfl_xor(s, st);
        s2 += __shfl_xor(s2, st);
    }
    if (ln == 0) {
        Se[i] = (float)s;
        atomicMax(&MelU[i >> 10], __float_as_uint((float)s2));
    }
}

// ---------------- paired-stage kernel: stages q0,q0+1; residual in dedicated LDS ------
// R9 hi-only base (76 VGPR, depth-2 B-hi prefetch). NEW: runtime (NOT unrolled -- R7's
// unroll caused the 128-VGPR spill) loop over 2 stages; residual rows live in a
// dedicated rbuf[32][256] LDS array (not aliased with the scratch union), so rerank /
// overflow / epilogue read LDS, and the mid-pair 32MB HBM write + 26MB re-read vanish.
// qs=0 loader reads global + populates rbuf; qs=1 loader reads rbuf; only qs=1
// epilogue writes global. All consumers see bit-identical f32 values -> indices
// bitwise unchanged; only loss fp64 partial-sum grouping changes (2 stages/atomic).

__launch_bounds__(512, 2)
__global__ void k_stagepair(const float* __restrict__ cb,
                            const uint4* __restrict__ Bfrag,
                            const float* __restrict__ Se,
                            const float* __restrict__ Mel,
                            float* __restrict__ residual,
                            float* __restrict__ out,
                            double* __restrict__ lossAcc,
                            int q0) {
    __shared__ float rbuf[ROWS][256];                     // 32 KB persistent rows
    __shared__ union {
        uint4 afr[2048];                                  // 32 KB A-frags (filter phase)
        struct { int slist[32][16]; float sdd[32][16];
                 int srow[512]; int sslot[512]; } post;   // post-filter (16 KB)
        struct { float ovd[512]; int ovk[512]; } over;    // overflow fallback (4 KB)
        double lred[8];                                   // loss partials
    } sc;
    __shared__ float seL[1024];                           // 4 KB
    __shared__ float srb[32], margin[32];
    __shared__ unsigned sminI[32];
    __shared__ int   scount[32], sidx[32];
    __shared__ int   nSurv;

    const int tid  = threadIdx.x;
    const int lane = tid & 63;
    const int w    = tid >> 6;          // wave 0..7
    const int quad = lane >> 4;
    const int lc   = lane & 15;
    const int row0 = blockIdx.x * ROWS;
    const int g    = tid >> 8;          // half-block 0/1
    const int dt   = tid & 255;

    double lsum = 0.0;                  // loss across both stages

    for (int qs = 0; qs < 2; ++qs) {    // runtime loop: do NOT unroll (VGPR pressure)
        const int q = q0 + qs;

        // ---- per-stage resets + Se staging ----
        if (tid < 32) { scount[tid] = 0; sminI[tid] = 0xFFFFFFFFu; }
        if (tid == 32) nSurv = 0;
        seL[tid]       = Se[q * K_ + tid];
        seL[tid + 512] = Se[q * K_ + tid + 512];
        const float melq4 = 4.04f * sqrtf(Mel[q]);

        // ---- early B prefetch (hi of tiles it=0,1 of this wave) ----
        const uint4* __restrict__ Bq = Bfrag + (size_t)q * (64 * 8 * 2 * 64);
        U4S8 b0h, b1h;
        {
            const uint4* p0 = Bq + (((size_t)((w * 8 + 0) * 8 + 0)) * 2) * 64 + lane;
            b0h.u = p0[0];
            const uint4* p1 = Bq + (((size_t)((w * 8 + 1) * 8 + 0)) * 2) * 64 + lane;
            b1h.u = p1[0];
        }

        // ---- FUSED loader: Sr (fp64) + Sum|r| + A-frag build; qs=0 from global
        //      (also fills rbuf), qs=1 from rbuf. Bit-identical either way. ----
        {
            int row = tid >> 4, seg = tid & 15;
            int rg = row >> 4, rlo = row & 15;
            int kc = seg >> 1, par = seg & 1;
            float4v v0, v1, v2, v3;
            if (qs == 0) {
                const float* rp = residual + (size_t)(row0 + row) * D_ + seg * 16;
                v0 = *(const float4v*)(rp);
                v1 = *(const float4v*)(rp + 4);
                v2 = *(const float4v*)(rp + 8);
                v3 = *(const float4v*)(rp + 12);
                float* lp = &rbuf[row][seg * 16];
                *(float4v*)(lp)      = v0;
                *(float4v*)(lp + 4)  = v1;
                *(float4v*)(lp + 8)  = v2;
                *(float4v*)(lp + 12) = v3;
            } else {
                const float* lp = &rbuf[row][seg * 16];
                v0 = *(const float4v*)(lp);
                v1 = *(const float4v*)(lp + 4);
                v2 = *(const float4v*)(lp + 8);
                v3 = *(const float4v*)(lp + 12);
            }
            float vv[16] = {v0.x, v0.y, v0.z, v0.w, v1.x, v1.y, v1.z, v1.w,
                            v2.x, v2.y, v2.z, v2.w, v3.x, v3.y, v3.z, v3.w};
            double s = 0.0; float sa = 0.0f;
            #pragma unroll
            for (int i = 0; i < 16; ++i) {
                float v = vv[i];
                s += (double)(v * v);
                sa += fabsf(v);
            }
            #pragma unroll
            for (int st = 8; st > 0; st >>= 1) {
                s  += __shfl_xor(s, st);
                sa += __shfl_xor(sa, st);
            }
            if (seg == 0) {
                float sr = (float)s;
                float sb = sa * 1.001f;
                srb[row]    = sr;
                margin[row] = 9.6e-7f * sr + 4.0e-7f * sb + 2.0e-4f
                            + melq4 * sqrtf(sr);
            }
            // afr slot = blk*64 + (ln ^ kc); XOR spreads write banks; reads stay a
            // permutation of a contiguous 64-block.
            #pragma unroll
            for (int h = 0; h < 2; ++h) {
                unsigned short hh[8], ll[8];
                #pragma unroll
                for (int j = 0; j < 8; ++j) {
                    float v = vv[h * 8 + j];
                    hh[j] = f2bf(v);
                    ll[j] = f2bf(v - bf2f(hh[j]));
                }
                uint4 hiW, loW;
                hiW.x = (unsigned)hh[0] | ((unsigned)hh[1] << 16);
                hiW.y = (unsigned)hh[2] | ((unsigned)hh[3] << 16);
                hiW.z = (unsigned)hh[4] | ((unsigned)hh[5] << 16);
                hiW.w = (unsigned)hh[6] | ((unsigned)hh[7] << 16);
                loW.x = (unsigned)ll[0] | ((unsigned)ll[1] << 16);
                loW.y = (unsigned)ll[2] | ((unsigned)ll[3] << 16);
                loW.z = (unsigned)ll[4] | ((unsigned)ll[5] << 16);
                loW.w = (unsigned)ll[6] | ((unsigned)ll[7] << 16);
                int ln = (par * 2 + h) * 16 + rlo;
                int sl = ln ^ kc;
                sc.afr[((rg * 8 + kc) * 2 + 0) * 64 + sl] = hiW;
                sc.afr[((rg * 8 + kc) * 2 + 1) * 64 + sl] = loW;
            }
        }
        __syncthreads();

        // ---- MFMA filter: hi-only, 2 MFMAs per acc; depth-2 rolling B-hi prefetch ----
        float4v accA[16];
        #pragma unroll
        for (int i = 0; i < 16; ++i) accA[i] = (float4v){0.f, 0.f, 0.f, 0.f};

        for (int kc = 0; kc < 8; ++kc) {
            U4S8 a0h, a0l, a1h, a1l;
            a0h.u = sc.afr[((0 * 8 + kc) * 2 + 0) * 64 + (lane ^ kc)];
            a0l.u = sc.afr[((0 * 8 + kc) * 2 + 1) * 64 + (lane ^ kc)];
            a1h.u = sc.afr[((1 * 8 + kc) * 2 + 0) * 64 + (lane ^ kc)];
            a1l.u = sc.afr[((1 * 8 + kc) * 2 + 1) * 64 + (lane ^ kc)];
            #pragma unroll
            for (int ctl = 0; ctl < 8; ++ctl) {
                U4S8 bh = ((ctl & 1) == 0) ? b0h : b1h;
                {   // prefetch it+2 (hi only) into the buffer just consumed
                    int pkc  = kc + ((ctl + 2) >> 3);
                    int pctl = (ctl + 2) & 7;
                    const uint4* p = Bq + (((size_t)((w * 8 + pctl) * 8 + pkc)) * 2) * 64 + lane;
                    if ((ctl & 1) == 0) b0h.u = p[0];
                    else                b1h.u = p[0];
                }
                float4v a0 = accA[ctl * 2 + 0];
                a0 = __builtin_amdgcn_mfma_f32_16x16x32_bf16(a0h.s, bh.s, a0, 0, 0, 0);
                a0 = __builtin_amdgcn_mfma_f32_16x16x32_bf16(a0l.s, bh.s, a0, 0, 0, 0);
                accA[ctl * 2 + 0] = a0;
                float4v a1 = accA[ctl * 2 + 1];
                a1 = __builtin_amdgcn_mfma_f32_16x16x32_bf16(a1h.s, bh.s, a1, 0, 0, 0);
                a1 = __builtin_amdgcn_mfma_f32_16x16x32_bf16(a1l.s, bh.s, a1, 0, 0, 0);
                accA[ctl * 2 + 1] = a1;
            }
        }

        // ---- per-lane mins; D layout: row = rg*16 + quad*4 + reg, col = lc ----
        float sr8[8];
        #pragma unroll
        for (int rr = 0; rr < 8; ++rr)
            sr8[rr] = srb[(rr >> 2) * 16 + quad * 4 + (rr & 3)];

        float mn[8];
        #pragma unroll
        for (int rr = 0; rr < 8; ++rr) mn[rr] = 3.4e38f;
        #pragma unroll
        for (int ctl = 0; ctl < 8; ++ctl) {
            int cand = (w * 8 + ctl) * 16 + lc;
            float se = seL[cand];
            #pragma unroll
            for (int rr = 0; rr < 8; ++rr) {
                float dd = (sr8[rr] + se) - 2.0f * accA[ctl * 2 + (rr >> 2)][rr & 3];
                mn[rr] = fminf(mn[rr], dd);
            }
        }
        #pragma unroll
        for (int rr = 0; rr < 8; ++rr) {
            float v = mn[rr];
            v = fminf(v, __shfl_xor(v, 1));
            v = fminf(v, __shfl_xor(v, 2));
            v = fminf(v, __shfl_xor(v, 4));
            v = fminf(v, __shfl_xor(v, 8));
            if (lc == 0)
                atomicMin(&sminI[(rr >> 2) * 16 + quad * 4 + (rr & 3)], fkey(v));
        }
        __syncthreads();

        // ---- survivor collection (thr = exact block min + margin) ----
        float thrV[8];
        #pragma unroll
        for (int rr = 0; rr < 8; ++rr) {
            int row = (rr >> 2) * 16 + quad * 4 + (rr & 3);
            thrV[rr] = fkeyinv(sminI[row]) + margin[row];
        }
        #pragma unroll
        for (int ctl = 0; ctl < 8; ++ctl) {
            int cand = (w * 8 + ctl) * 16 + lc;
            float se = seL[cand];
            #pragma unroll
            for (int rr = 0; rr < 8; ++rr) {
                int row = (rr >> 2) * 16 + quad * 4 + (rr & 3);
                float dd = (sr8[rr] + se) - 2.0f * accA[ctl * 2 + (rr >> 2)][rr & 3];
                if (dd <= thrV[rr]) {
                    int p = atomicAdd(&scount[row], 1);
                    if (p < 16) sc.post.slist[row][p] = cand;
                }
            }
        }
        __syncthreads();

        // ---- compact survivors; cnt==1 rows resolved immediately ----
        if (tid < 32) {
            int cnt = scount[tid];
            if (cnt == 1) {
                sidx[tid] = sc.post.slist[tid][0];
            } else if (cnt >= 2 && cnt <= 16) {
                int base = atomicAdd(&nSurv, cnt);
                for (int s2 = 0; s2 < cnt; ++s2) {
                    sc.post.srow[base + s2]  = tid;
                    sc.post.sslot[base + s2] = s2;
                }
            }
        }
        __syncthreads();

        // ---- exact fp64 re-rank: 16 lanes per survivor; E from L2, r from rbuf ----
        {
            int nS  = nSurv;
            int grp = tid >> 4, ln = tid & 15;
            for (int j = grp; j < nS; j += 32) {
                int row  = sc.post.srow[j];
                int slot = sc.post.sslot[j];
                int k    = sc.post.slist[row][slot];
                const float* Ek = cb + ((size_t)q * K_ + k) * D_ + ln * 16;
                const float* Rk = &rbuf[row][ln * 16];
                float4v e0 = *(const float4v*)(Ek);
                float4v e1 = *(const float4v*)(Ek + 4);
                float4v e2 = *(const float4v*)(Ek + 8);
                float4v e3 = *(const float4v*)(Ek + 12);
                float4v r0 = *(const float4v*)(Rk);
                float4v r1 = *(const float4v*)(Rk + 4);
                float4v r2 = *(const float4v*)(Rk + 8);
                float4v r3 = *(const float4v*)(Rk + 12);
                float ev[16] = {e0.x, e0.y, e0.z, e0.w, e1.x, e1.y, e1.z, e1.w,
                                e2.x, e2.y, e2.z, e2.w, e3.x, e3.y, e3.z, e3.w};
                float rv2[16] = {r0.x, r0.y, r0.z, r0.w, r1.x, r1.y, r1.z, r1.w,
                                 r2.x, r2.y, r2.z, r2.w, r3.x, r3.y, r3.z, r3.w};
                double a0 = 0.0, a1 = 0.0;
                #pragma unroll
                for (int d = 0; d < 16; d += 2) {
                    a0 = fma((double)ev[d],     (double)rv2[d],     a0);
                    a1 = fma((double)ev[d + 1], (double)rv2[d + 1], a1);
                }
                double ssum = a0 + a1;
                #pragma unroll
                for (int st = 8; st > 0; st >>= 1) ssum += __shfl_xor(ssum, st);
                if (ln == 0) {
                    float dotf = (float)ssum;
                    float V = srb[row] + seL[k];
                    sc.post.sdd[row][slot] = V - 2.0f * dotf;
                }
            }
        }
        __syncthreads();
        if (tid < 32) {
            int cnt = scount[tid];
            if (cnt >= 2 && cnt <= 16) {
                float bd = 3.4e38f; int bk = 0x7fffffff;
                for (int s2 = 0; s2 < cnt; ++s2) {
                    float dv = sc.post.sdd[tid][s2]; int kv = sc.post.slist[tid][s2];
                    if (dv < bd || (dv == bd && kv < bk)) { bd = dv; bk = kv; }
                }
                sidx[tid] = bk;
            }
        }
        __syncthreads();

        // ---- overflow fallback (>16 survivors; exact, block-wide, rare) ----
        for (int row = 0; row < ROWS; ++row) {
            int cnt = scount[row];
            if (cnt <= 16) continue;
            float bd = 3.4e38f; int bk = K_;
            #pragma unroll
            for (int c = 0; c < 2; ++c) {
                int k = tid * 2 + c;
                const float* Ek = cb + ((size_t)q * K_ + k) * D_;
                double a0 = 0.0, a1 = 0.0;
                for (int d = 0; d < D_; d += 2) {
                    a0 = fma((double)Ek[d],     (double)rbuf[row][d],     a0);
                    a1 = fma((double)Ek[d + 1], (double)rbuf[row][d + 1], a1);
                }
                float dd = (srb[row] + seL[k]) - 2.0f * (float)(a0 + a1);
                if (dd < bd || (dd == bd && k < bk)) { bd = dd; bk = k; }
            }
            sc.over.ovd[tid] = bd; sc.over.ovk[tid] = bk;
            __syncthreads();
            for (int st = 256; st > 0; st >>= 1) {
                if (tid < st) {
                    float od = sc.over.ovd[tid + st]; int ok = sc.over.ovk[tid + st];
                    if (od < sc.over.ovd[tid] ||
                        (od == sc.over.ovd[tid] && ok < sc.over.ovk[tid])) {
                        sc.over.ovd[tid] = od; sc.over.ovk[tid] = ok;
                    }
                }
                __syncthreads();
            }
            if (tid == 0) sidx[row] = sc.over.ovk[0];
            __syncthreads();
        }

        // ---- epilogue: exact fp32 STE update in rbuf; global write only on qs==1 ----
        // each (row,dt) element is owned by exactly one thread: no barrier needed here
        const float* Eq = cb + (size_t)q * K_ * D_;
        #pragma unroll
        for (int jj = 0; jj < 16; ++jj) {
            int row = g * 16 + jj;
            int idx = sidx[row];
            float rv   = rbuf[row][dt];
            float zq   = Eq[(size_t)idx * D_ + dt];
            float t1   = zq - rv;
            float zqst = rv + t1;
            float nr   = rv - zqst;
            rbuf[row][dt] = nr;
            if (qs == 1)
                residual[(size_t)(row0 + row) * D_ + dt] = nr;
            lsum += (double)t1 * (double)t1;
        }
        if (tid < 32) out[IDX_OFF + q * BT_ + row0 + tid] = (float)sidx[tid];

        __syncthreads();   // rbuf update + union death before next stage resets
    }

    // ---- loss: wave shuffle reduce + 8 partials, one atomic per block-pair ----
    #pragma unroll
    for (int st = 32; st > 0; st >>= 1) lsum += __shfl_xor(lsum, st);
    if (lane == 0) sc.lred[w] = lsum;
    __syncthreads();
    if (tid == 0) {
        double t = 0.0;
        #pragma unroll
        for (int i = 0; i < 8; ++i) t += sc.lred[i];
        atomicAdd(lossAcc, t);
    }
}

// ---------------- emit: out[b,d,t] = z[b,d,t] - r_final[b,t,d] ----------------

__global__ void k_emit(const float* __restrict__ z, const float* __restrict__ residual,
                       float* __restrict__ out) {
    __shared__ float tile[32][33];
    int b  = blockIdx.z;
    int t0 = blockIdx.y * 32;
    int d0 = blockIdx.x * 32;
    int tx = threadIdx.x & 31;
    int ty = threadIdx.x >> 5;
    const float* rb = residual + (size_t)b * T_ * D_;
    #pragma unroll
    for (int r = 0; r < 32; r += 8)
        tile[ty + r][tx] = rb[(size_t)(t0 + ty + r) * D_ + d0 + tx];
    __syncthreads();
    const float* zb = z + (size_t)b * D_ * T_;
    float* ob = out + (size_t)b * D_ * T_;
    #pragma unroll
    for (int r = 0; r < 32; r += 8) {
        size_t off = (size_t)(d0 + ty + r) * T_ + t0 + tx;
        ob[off] = zb[off] - tile[tx][ty + r];
    }
}

__global__ void k_final(const double* lossAcc, float* out) {
    if (threadIdx.x == 0 && blockIdx.x == 0) {
        double m = *lossAcc / (double)N_;
        out[LOSS_OFF] = (float)(1.25 * m);
    }
}

// ---------------- launcher ----------------

extern "C" void kernel_launch(void* const* d_in, const int* in_sizes, int n_in,
                              void* d_out, int out_size, void* d_ws, size_t ws_size,
                              hipStream_t stream) {
    const float* z  = (const float*)d_in[0];
    const float* cb = (const float*)d_in[1];
    float* out = (float*)d_out;

    // ws layout: residual f32[N_] (32MB) | Bfrag uint4 (8MB) | Se f32[Q*K]
    //            | loss double | MelU u32[Q]
    float*  residual = (float*)d_ws;
    uint4*  Bfrag    = (uint4*)((char*)d_ws + (size_t)N_ * 4);
    float*  Se       = (float*)((char*)d_ws + (size_t)N_ * 4 + (size_t)8 * 1024 * 1024);
    double* lossAcc  = (double*)((char*)d_ws + (size_t)N_ * 4 + (size_t)8 * 1024 * 1024
                                 + (size_t)Q_ * K_ * 4);
    unsigned* MelU   = (unsigned*)((char*)lossAcc + 8);

    hipLaunchKernelGGL(k_init, dim3(T_ / 32, D_ / 32, B_), dim3(256), 0, stream,
                       z, residual, lossAcc, MelU);
    hipLaunchKernelGGL(k_bfrag, dim3(1024), dim3(256), 0, stream, cb, Bfrag);
    hipLaunchKernelGGL(k_se, dim3((Q_ * K_ * 16 + 255) / 256), dim3(256), 0, stream,
                       cb, Se, MelU);
    for (int q0 = 0; q0 < Q_; q0 += 2) {
        hipLaunchKernelGGL(k_stagepair, dim3(BT_ / ROWS), dim3(512), 0, stream,
                           cb, Bfrag, Se, (const float*)MelU, residual, out, lossAcc, q0);
    }
    hipLaunchKernelGGL(k_emit, dim3(D_ / 32, T_ / 32, B_), dim3(256), 0, stream,
                       z, residual, out);
    hipLaunchKernelGGL(k_final, dim3(1), dim3(256), 0, stream, lossAcc, out);
}

// Round 11
// 917.088 us; speedup vs baseline: 1.2151x; 1.2151x over previous
//
#include <hip/hip_runtime.h>

#define B_   8
#define D_   256
#define T_   4096
#define Q_   8
#define K_   1024
#define BT_  (B_*T_)            // 32768 rows
#define N_   (B_*T_*D_)         // 8388608 elements
#define LOSS_OFF N_
#define IDX_OFF  (N_+1)
#define ROWS 32                 // rows per block

typedef __attribute__((ext_vector_type(8))) short short8;
typedef __attribute__((ext_vector_type(4))) float float4v;

union U4S8 { uint4 u; short8 s; };

__device__ __forceinline__ unsigned short f2bf(float x) {
    unsigned int u = __float_as_uint(x);
    unsigned int r = (u + 0x7FFFu + ((u >> 16) & 1u)) >> 16;
    return (unsigned short)r;
}
__device__ __forceinline__ float bf2f(unsigned short b) {
    return __uint_as_float(((unsigned int)b) << 16);
}
// order-preserving float<->uint key (exact min via integer atomicMin)
__device__ __forceinline__ unsigned fkey(float f) {
    unsigned u = __float_as_uint(f);
    return (u & 0x80000000u) ? ~u : (u | 0x80000000u);
}
__device__ __forceinline__ float fkeyinv(unsigned k) {
    unsigned u = (k & 0x80000000u) ? (k & 0x7fffffffu) : ~k;
    return __uint_as_float(u);
}

// ---------------- init: z [B,D,T] -> residual [B,T,D], tiled transpose ----------------

__global__ void k_init(const float* __restrict__ z, float* __restrict__ residual,
                       double* lossAcc, unsigned* MelU) {
    __shared__ float tile[32][33];
    int b  = blockIdx.z;
    int d0 = blockIdx.y * 32;
    int t0 = blockIdx.x * 32;
    int tx = threadIdx.x & 31;
    int ty = threadIdx.x >> 5;
    const float* zb = z + (size_t)b * D_ * T_;
    #pragma unroll
    for (int r = 0; r < 32; r += 8)
        tile[ty + r][tx] = zb[(size_t)(d0 + ty + r) * T_ + t0 + tx];
    __syncthreads();
    float* rb = residual + (size_t)b * T_ * D_;
    #pragma unroll
    for (int r = 0; r < 32; r += 8)
        rb[(size_t)(t0 + ty + r) * D_ + d0 + tx] = tile[tx][ty + r];
    if (b == 0 && blockIdx.x == 0 && blockIdx.y == 0 && threadIdx.x == 0) {
        *lossAcc = 0.0;
        #pragma unroll
        for (int i = 0; i < Q_; ++i) MelU[i] = 0u;
    }
}

// ---------------- B-fragment precompute: cb -> bf16 hi/lo in MFMA lane layout ----------
// Layout: Bfrag[((q*64 + ct)*8 + kc)*2*64 + part*64 + lane] : uint4 (8 bf16)
// lane supplies B[k = kc*32 + (lane>>4)*8 + j][n = ct*16 + (lane&15)], j=0..7
// (lo part still written but no longer read by k_stage -- hi-only filter.)

__global__ void k_bfrag(const float* __restrict__ cb, uint4* __restrict__ Bfrag) {
    int gid = blockIdx.x * 256 + threadIdx.x;      // 262144 total
    int q    = gid >> 15;
    int rem  = gid & 32767;
    int ct   = rem >> 9;
    int kc   = (rem >> 6) & 7;
    int lane = rem & 63;
    int cand = ct * 16 + (lane & 15);
    int kb   = kc * 32 + (lane >> 4) * 8;
    const float* e = cb + ((size_t)q * K_ + cand) * D_ + kb;
    float4v u0 = *(const float4v*)(e);
    float4v u1 = *(const float4v*)(e + 4);
    float vv[8] = {u0.x, u0.y, u0.z, u0.w, u1.x, u1.y, u1.z, u1.w};
    unsigned short h[8], l[8];
    #pragma unroll
    for (int j = 0; j < 8; ++j) {
        float v = vv[j];
        h[j] = f2bf(v);
        l[j] = f2bf(v - bf2f(h[j]));
    }
    uint4 hi, lo;
    hi.x = (unsigned)h[0] | ((unsigned)h[1] << 16);
    hi.y = (unsigned)h[2] | ((unsigned)h[3] << 16);
    hi.z = (unsigned)h[4] | ((unsigned)h[5] << 16);
    hi.w = (unsigned)h[6] | ((unsigned)h[7] << 16);
    lo.x = (unsigned)l[0] | ((unsigned)l[1] << 16);
    lo.y = (unsigned)l[2] | ((unsigned)l[3] << 16);
    lo.z = (unsigned)l[4] | ((unsigned)l[5] << 16);
    lo.w = (unsigned)l[6] | ((unsigned)l[7] << 16);
    size_t base = (((size_t)(q * 64 + ct) * 8 + kc) * 2) * 64;
    Bfrag[base + lane]      = hi;
    Bfrag[base + 64 + lane] = lo;
}

// ---------------- S_e (fp64 sum of fl32(e^2)) + per-stage max bf16-residual norm ------

__global__ void k_se(const float* __restrict__ cb, float* __restrict__ Se,
                     unsigned* __restrict__ MelU) {
    int gid = blockIdx.x * 256 + threadIdx.x;      // Q*K*16 = 131072 threads
    int i  = gid >> 4;
    int ln = gid & 15;
    if (i >= Q_ * K_) return;
    const float* e = cb + (size_t)i * D_ + ln * 16;
    float4v v0 = *(const float4v*)(e);
    float4v v1 = *(const float4v*)(e + 4);
    float4v v2 = *(const float4v*)(e + 8);
    float4v v3 = *(const float4v*)(e + 12);
    float vv[16] = {v0.x, v0.y, v0.z, v0.w, v1.x, v1.y, v1.z, v1.w,
                    v2.x, v2.y, v2.z, v2.w, v3.x, v3.y, v3.z, v3.w};
    double s = 0.0, s2 = 0.0;
    #pragma unroll
    for (int d = 0; d < 16; ++d) {
        float v = vv[d];
        float a = v * v;
        s += (double)a;
        float el = v - bf2f(f2bf(v));
        s2 += (double)(el * el);
    }
    #pragma unroll
    for (int st = 8; st > 0; st >>= 1) {
        s  += __shfl_xor(s, st);
        s2 += __shfl_xor(s2, st);
    }
    if (ln == 0) {
        Se[i] = (float)s;
        atomicMax(&MelU[i >> 10], __float_as_uint((float)s2));
    }
}

// ---------------- per-stage kernel: hi-only MFMA filter + fp64 re-rank ----------------
// R9 base (hi-only filter, 76 VGPR, depth-2 B-hi prefetch). ONE change:
// __launch_bounds__(512, 2) -> (512, 3). Diagnosis (R9 counters): MfmaUtil 13.8% +
// VALUBusy 21.9% + HBM 7.4% => ~65% of cycles NO pipe busy -- latency/barrier-bound
// at 2 blocks/CU. 3 blocks/CU (24 waves, VGPR cap 85 >= our 76; LDS 3x37.9KB < 160KB)
// adds 1.5x independent-block TLP to fill the phase-transition bubbles.
// Pair-fusion is 3-for-3 fatal (R7/R10: VGPR cap + LDS bank conflicts) -- abandoned.

__launch_bounds__(512, 3)
__global__ void k_stage(const float* __restrict__ cb,
                        const uint4* __restrict__ Bfrag,
                        const float* __restrict__ Se,
                        const float* __restrict__ Mel,
                        float* __restrict__ residual,
                        float* __restrict__ out,
                        double* __restrict__ lossAcc,
                        int q) {
    __shared__ union {
        uint4 afr[2048];                                  // 32 KB A-frags (filter phase)
        struct { int slist[32][16]; float sdd[32][16];
                 int srow[512]; int sslot[512]; } post;   // post-filter (8 KB)
        struct { float ovd[512]; int ovk[512]; } over;    // overflow fallback
        double lred[8];                                   // loss partials
    } sc;
    __shared__ float seL[1024];                           // 4 KB
    __shared__ float srb[32], margin[32];
    __shared__ unsigned sminI[32];
    __shared__ int   scount[32], sidx[32];
    __shared__ int   nSurv;

    const int tid  = threadIdx.x;
    const int lane = tid & 63;
    const int w    = tid >> 6;          // wave 0..7
    const int quad = lane >> 4;
    const int lc   = lane & 15;
    const int row0 = blockIdx.x * ROWS;
    const int g    = tid >> 8;          // half-block 0/1
    const int dt   = tid & 255;

    if (tid < 32) { scount[tid] = 0; sminI[tid] = 0xFFFFFFFFu; }
    if (tid == 32) nSurv = 0;
    seL[tid]       = Se[q * K_ + tid];
    seL[tid + 512] = Se[q * K_ + tid + 512];
    const float melq4 = 4.04f * sqrtf(Mel[q]);   // margin term for dropped r.el

    // ---- early B prefetch (hi of tiles it=0,1 of this wave) ----
    const uint4* __restrict__ Bq = Bfrag + (size_t)q * (64 * 8 * 2 * 64);
    U4S8 b0h, b1h;
    {
        const uint4* p0 = Bq + (((size_t)((w * 8 + 0) * 8 + 0)) * 2) * 64 + lane;
        b0h.u = p0[0];
        const uint4* p1 = Bq + (((size_t)((w * 8 + 1) * 8 + 0)) * 2) * 64 + lane;
        b1h.u = p1[0];
    }

    // ---- FUSED: Sr (fp64) + Sum|r| + A-frag bf16 hi/lo build, single global pass ----
    // pairing order st=8,4,2,1 reproduces the prior association bitwise.
    {
        int row = tid >> 4, seg = tid & 15;
        int rg = row >> 4, rlo = row & 15;
        int kc = seg >> 1, par = seg & 1;
        const float* rp = residual + (size_t)(row0 + row) * D_ + seg * 16;
        float4v v0 = *(const float4v*)(rp);
        float4v v1 = *(const float4v*)(rp + 4);
        float4v v2 = *(const float4v*)(rp + 8);
        float4v v3 = *(const float4v*)(rp + 12);
        float vv[16] = {v0.x, v0.y, v0.z, v0.w, v1.x, v1.y, v1.z, v1.w,
                        v2.x, v2.y, v2.z, v2.w, v3.x, v3.y, v3.z, v3.w};
        double s = 0.0; float sa = 0.0f;
        #pragma unroll
        for (int i = 0; i < 16; ++i) {
            float v = vv[i];
            s += (double)(v * v);
            sa += fabsf(v);
        }
        #pragma unroll
        for (int st = 8; st > 0; st >>= 1) {
            s  += __shfl_xor(s, st);
            sa += __shfl_xor(sa, st);
        }
        if (seg == 0) {
            float sr = (float)s;
            float sb = sa * 1.001f;
            srb[row]    = sr;
            margin[row] = 9.6e-7f * sr + 4.0e-7f * sb + 2.0e-4f
                        + melq4 * sqrtf(sr);
        }
        // A-frag writes: afr slot = blk*64 + (ln ^ kc); XOR spreads write banks,
        // reads (per fixed blk,kc) remain a permutation of a contiguous 64-block.
        #pragma unroll
        for (int h = 0; h < 2; ++h) {
            unsigned short hh[8], ll[8];
            #pragma unroll
            for (int j = 0; j < 8; ++j) {
                float v = vv[h * 8 + j];
                hh[j] = f2bf(v);
                ll[j] = f2bf(v - bf2f(hh[j]));
            }
            uint4 hiW, loW;
            hiW.x = (unsigned)hh[0] | ((unsigned)hh[1] << 16);
            hiW.y = (unsigned)hh[2] | ((unsigned)hh[3] << 16);
            hiW.z = (unsigned)hh[4] | ((unsigned)hh[5] << 16);
            hiW.w = (unsigned)hh[6] | ((unsigned)hh[7] << 16);
            loW.x = (unsigned)ll[0] | ((unsigned)ll[1] << 16);
            loW.y = (unsigned)ll[2] | ((unsigned)ll[3] << 16);
            loW.z = (unsigned)ll[4] | ((unsigned)ll[5] << 16);
            loW.w = (unsigned)ll[6] | ((unsigned)ll[7] << 16);
            int ln = (par * 2 + h) * 16 + rlo;
            int sl = ln ^ kc;
            sc.afr[((rg * 8 + kc) * 2 + 0) * 64 + sl] = hiW;
            sc.afr[((rg * 8 + kc) * 2 + 1) * 64 + sl] = loW;
        }
    }
    __syncthreads();

    // ---- MFMA filter: wave w covers cand-tiles w*8..w*8+7, both row-groups ----
    // flat it = kc*8+ctl; depth-2 rolling B-hi prefetch (tail reads <=2 tiles past
    // end -- in-bounds of Bq, values discarded). 2 MFMAs per acc: ah.bh + al.bh.
    float4v accA[16];
    #pragma unroll
    for (int i = 0; i < 16; ++i) accA[i] = (float4v){0.f, 0.f, 0.f, 0.f};

    for (int kc = 0; kc < 8; ++kc) {
        U4S8 a0h, a0l, a1h, a1l;
        a0h.u = sc.afr[((0 * 8 + kc) * 2 + 0) * 64 + (lane ^ kc)];
        a0l.u = sc.afr[((0 * 8 + kc) * 2 + 1) * 64 + (lane ^ kc)];
        a1h.u = sc.afr[((1 * 8 + kc) * 2 + 0) * 64 + (lane ^ kc)];
        a1l.u = sc.afr[((1 * 8 + kc) * 2 + 1) * 64 + (lane ^ kc)];
        #pragma unroll
        for (int ctl = 0; ctl < 8; ++ctl) {
            U4S8 bh = ((ctl & 1) == 0) ? b0h : b1h;
            // prefetch it+2 (hi only) into the buffer just consumed
            {
                int pkc  = kc + ((ctl + 2) >> 3);
                int pctl = (ctl + 2) & 7;
                const uint4* p = Bq + (((size_t)((w * 8 + pctl) * 8 + pkc)) * 2) * 64 + lane;
                if ((ctl & 1) == 0) b0h.u = p[0];
                else                b1h.u = p[0];
            }
            float4v a0 = accA[ctl * 2 + 0];
            a0 = __builtin_amdgcn_mfma_f32_16x16x32_bf16(a0h.s, bh.s, a0, 0, 0, 0);
            a0 = __builtin_amdgcn_mfma_f32_16x16x32_bf16(a0l.s, bh.s, a0, 0, 0, 0);
            accA[ctl * 2 + 0] = a0;
            float4v a1 = accA[ctl * 2 + 1];
            a1 = __builtin_amdgcn_mfma_f32_16x16x32_bf16(a1h.s, bh.s, a1, 0, 0, 0);
            a1 = __builtin_amdgcn_mfma_f32_16x16x32_bf16(a1l.s, bh.s, a1, 0, 0, 0);
            accA[ctl * 2 + 1] = a1;
        }
    }

    // ---- per-lane mins over tiles; D layout: row = rg*16 + quad*4 + reg, col = lc ----
    float sr8[8];
    #pragma unroll
    for (int rr = 0; rr < 8; ++rr)
        sr8[rr] = srb[(rr >> 2) * 16 + quad * 4 + (rr & 3)];

    float mn[8];
    #pragma unroll
    for (int rr = 0; rr < 8; ++rr) mn[rr] = 3.4e38f;
    #pragma unroll
    for (int ctl = 0; ctl < 8; ++ctl) {
        int cand = (w * 8 + ctl) * 16 + lc;
        float se = seL[cand];
        #pragma unroll
        for (int rr = 0; rr < 8; ++rr) {
            float dd = (sr8[rr] + se) - 2.0f * accA[ctl * 2 + (rr >> 2)][rr & 3];
            mn[rr] = fminf(mn[rr], dd);
        }
    }
    #pragma unroll
    for (int rr = 0; rr < 8; ++rr) {
        float v = mn[rr];
        v = fminf(v, __shfl_xor(v, 1));
        v = fminf(v, __shfl_xor(v, 2));
        v = fminf(v, __shfl_xor(v, 4));
        v = fminf(v, __shfl_xor(v, 8));
        if (lc == 0)
            atomicMin(&sminI[(rr >> 2) * 16 + quad * 4 + (rr & 3)], fkey(v));
    }
    __syncthreads();

    // ---- survivor collection (thr = exact block min + margin) ----
    float thrV[8];
    #pragma unroll
    for (int rr = 0; rr < 8; ++rr) {
        int row = (rr >> 2) * 16 + quad * 4 + (rr & 3);
        thrV[rr] = fkeyinv(sminI[row]) + margin[row];
    }
    #pragma unroll
    for (int ctl = 0; ctl < 8; ++ctl) {
        int cand = (w * 8 + ctl) * 16 + lc;
        float se = seL[cand];
        #pragma unroll
        for (int rr = 0; rr < 8; ++rr) {
            int row = (rr >> 2) * 16 + quad * 4 + (rr & 3);
            float dd = (sr8[rr] + se) - 2.0f * accA[ctl * 2 + (rr >> 2)][rr & 3];
            if (dd <= thrV[rr]) {
                int p = atomicAdd(&scount[row], 1);
                if (p < 16) sc.post.slist[row][p] = cand;
            }
        }
    }
    __syncthreads();

    // ---- compact survivors block-wide; cnt==1 rows resolved immediately ----
    if (tid < 32) {
        int cnt = scount[tid];
        if (cnt == 1) {
            sidx[tid] = sc.post.slist[tid][0];
        } else if (cnt >= 2 && cnt <= 16) {
            int base = atomicAdd(&nSurv, cnt);
            for (int s2 = 0; s2 < cnt; ++s2) {
                sc.post.srow[base + s2]  = tid;
                sc.post.sslot[base + s2] = s2;
            }
        }
    }
    __syncthreads();

    // ---- exact fp64 re-rank: 16 lanes per survivor, vectorized loads ----
    {
        int nS  = nSurv;
        int grp = tid >> 4, ln = tid & 15;
        for (int j = grp; j < nS; j += 32) {
            int row  = sc.post.srow[j];
            int slot = sc.post.sslot[j];
            int k    = sc.post.slist[row][slot];
            const float* Ek = cb + ((size_t)q * K_ + k) * D_ + ln * 16;
            const float* Rk = residual + (size_t)(row0 + row) * D_ + ln * 16;
            float4v e0 = *(const float4v*)(Ek);
            float4v e1 = *(const float4v*)(Ek + 4);
            float4v e2 = *(const float4v*)(Ek + 8);
            float4v e3 = *(const float4v*)(Ek + 12);
            float4v r0 = *(const float4v*)(Rk);
            float4v r1 = *(const float4v*)(Rk + 4);
            float4v r2 = *(const float4v*)(Rk + 8);
            float4v r3 = *(const float4v*)(Rk + 12);
            float ev[16] = {e0.x, e0.y, e0.z, e0.w, e1.x, e1.y, e1.z, e1.w,
                            e2.x, e2.y, e2.z, e2.w, e3.x, e3.y, e3.z, e3.w};
            float rv2[16] = {r0.x, r0.y, r0.z, r0.w, r1.x, r1.y, r1.z, r1.w,
                             r2.x, r2.y, r2.z, r2.w, r3.x, r3.y, r3.z, r3.w};
            double a0 = 0.0, a1 = 0.0;
            #pragma unroll
            for (int d = 0; d < 16; d += 2) {
                a0 = fma((double)ev[d],     (double)rv2[d],     a0);
                a1 = fma((double)ev[d + 1], (double)rv2[d + 1], a1);
            }
            double ssum = a0 + a1;
            #pragma unroll
            for (int st = 8; st > 0; st >>= 1) ssum += __shfl_xor(ssum, st);
            if (ln == 0) {
                float dotf = (float)ssum;
                float V = srb[row] + seL[k];
                sc.post.sdd[row][slot] = V - 2.0f * dotf;
            }
        }
    }
    __syncthreads();
    if (tid < 32) {
        int cnt = scount[tid];
        if (cnt >= 2 && cnt <= 16) {
            float bd = 3.4e38f; int bk = 0x7fffffff;
            for (int s2 = 0; s2 < cnt; ++s2) {
                float dv = sc.post.sdd[tid][s2]; int kv = sc.post.slist[tid][s2];
                if (dv < bd || (dv == bd && kv < bk)) { bd = dv; bk = kv; }
            }
            sidx[tid] = bk;
        }
    }
    __syncthreads();

    // ---- overflow fallback (>16 survivors; exact, block-wide, rare) ----
    for (int row = 0; row < ROWS; ++row) {
        int cnt = scount[row];
        if (cnt <= 16) continue;
        const float* Rr = residual + (size_t)(row0 + row) * D_;
        float bd = 3.4e38f; int bk = K_;
        #pragma unroll
        for (int c = 0; c < 2; ++c) {
            int k = tid * 2 + c;
            const float* Ek = cb + ((size_t)q * K_ + k) * D_;
            double a0 = 0.0, a1 = 0.0;
            for (int d = 0; d < D_; d += 2) {
                a0 = fma((double)Ek[d],     (double)Rr[d],     a0);
                a1 = fma((double)Ek[d + 1], (double)Rr[d + 1], a1);
            }
            float dd = (srb[row] + seL[k]) - 2.0f * (float)(a0 + a1);
            if (dd < bd || (dd == bd && k < bk)) { bd = dd; bk = k; }
        }
        sc.over.ovd[tid] = bd; sc.over.ovk[tid] = bk;
        __syncthreads();
        for (int st = 256; st > 0; st >>= 1) {
            if (tid < st) {
                float od = sc.over.ovd[tid + st]; int ok = sc.over.ovk[tid + st];
                if (od < sc.over.ovd[tid] ||
                    (od == sc.over.ovd[tid] && ok < sc.over.ovk[tid])) {
                    sc.over.ovd[tid] = od; sc.over.ovk[tid] = ok;
                }
            }
            __syncthreads();
        }
        if (tid == 0) sidx[row] = sc.over.ovk[0];
        __syncthreads();
    }

    // ---- epilogue: exact fp32 STE residual update (bitwise as prior rounds) ----
    const float* Eq = cb + (size_t)q * K_ * D_;
    double lsum = 0.0;
    #pragma unroll
    for (int jj = 0; jj < 16; ++jj) {
        int row = g * 16 + jj;
        int idx = sidx[row];
        size_t roff = (size_t)(row0 + row) * D_ + dt;
        float rv   = residual[roff];
        float zq   = Eq[(size_t)idx * D_ + dt];
        float t1   = zq - rv;
        float zqst = rv + t1;
        residual[roff] = rv - zqst;
        lsum += (double)t1 * (double)t1;
    }
    if (tid < 32) out[IDX_OFF + q * BT_ + row0 + tid] = (float)sidx[tid];

    // ---- loss: wave shuffle reduce + 8 partials ----
    #pragma unroll
    for (int st = 32; st > 0; st >>= 1) lsum += __shfl_xor(lsum, st);
    __syncthreads();                     // union reuse: post/over dead
    if (lane == 0) sc.lred[w] = lsum;
    __syncthreads();
    if (tid == 0) {
        double t = 0.0;
        #pragma unroll
        for (int i = 0; i < 8; ++i) t += sc.lred[i];
        atomicAdd(lossAcc, t);
    }
}

// ---------------- emit: out[b,d,t] = z[b,d,t] - r_final[b,t,d] ----------------

__global__ void k_emit(const float* __restrict__ z, const float* __restrict__ residual,
                       float* __restrict__ out) {
    __shared__ float tile[32][33];
    int b  = blockIdx.z;
    int t0 = blockIdx.y * 32;
    int d0 = blockIdx.x * 32;
    int tx = threadIdx.x & 31;
    int ty = threadIdx.x >> 5;
    const float* rb = residual + (size_t)b * T_ * D_;
    #pragma unroll
    for (int r = 0; r < 32; r += 8)
        tile[ty + r][tx] = rb[(size_t)(t0 + ty + r) * D_ + d0 + tx];
    __syncthreads();
    const float* zb = z + (size_t)b * D_ * T_;
    float* ob = out + (size_t)b * D_ * T_;
    #pragma unroll
    for (int r = 0; r < 32; r += 8) {
        size_t off = (size_t)(d0 + ty + r) * T_ + t0 + tx;
        ob[off] = zb[off] - tile[tx][ty + r];
    }
}

__global__ void k_final(const double* lossAcc, float* out) {
    if (threadIdx.x == 0 && blockIdx.x == 0) {
        double m = *lossAcc / (double)N_;
        out[LOSS_OFF] = (float)(1.25 * m);
    }
}

// ---------------- launcher ----------------

extern "C" void kernel_launch(void* const* d_in, const int* in_sizes, int n_in,
                              void* d_out, int out_size, void* d_ws, size_t ws_size,
                              hipStream_t stream) {
    const float* z  = (const float*)d_in[0];
    const float* cb = (const float*)d_in[1];
    float* out = (float*)d_out;

    // ws layout: residual f32[N_] (32MB) | Bfrag uint4 (8MB) | Se f32[Q*K]
    //            | loss double | MelU u32[Q]
    float*  residual = (float*)d_ws;
    uint4*  Bfrag    = (uint4*)((char*)d_ws + (size_t)N_ * 4);
    float*  Se       = (float*)((char*)d_ws + (size_t)N_ * 4 + (size_t)8 * 1024 * 1024);
    double* lossAcc  = (double*)((char*)d_ws + (size_t)N_ * 4 + (size_t)8 * 1024 * 1024
                                 + (size_t)Q_ * K_ * 4);
    unsigned* MelU   = (unsigned*)((char*)lossAcc + 8);

    hipLaunchKernelGGL(k_init, dim3(T_ / 32, D_ / 32, B_), dim3(256), 0, stream,
                       z, residual, lossAcc, MelU);
    hipLaunchKernelGGL(k_bfrag, dim3(1024), dim3(256), 0, stream, cb, Bfrag);
    hipLaunchKernelGGL(k_se, dim3((Q_ * K_ * 16 + 255) / 256), dim3(256), 0, stream,
                       cb, Se, MelU);
    for (int q = 0; q < Q_; ++q) {
        hipLaunchKernelGGL(k_stage, dim3(BT_ / ROWS), dim3(512), 0, stream,
                           cb, Bfrag, Se, (const float*)MelU, residual, out, lossAcc, q);
    }
    hipLaunchKernelGGL(k_emit, dim3(D_ / 32, T_ / 32, B_), dim3(256), 0, stream,
                       z, residual, out);
    hipLaunchKernelGGL(k_final, dim3(1), dim3(256), 0, stream, lossAcc, out);
}

// Round 12
// 745.288 us; speedup vs baseline: 1.4952x; 1.2305x over previous
//
#include <hip/hip_runtime.h>

#define B_   8
#define D_   256
#define T_   4096
#define Q_   8
#define K_   1024
#define BT_  (B_*T_)            // 32768 rows
#define N_   (B_*T_*D_)         // 8388608 elements
#define LOSS_OFF N_
#define IDX_OFF  (N_+1)
#define ROWS 64                 // rows per block (4 row-groups of 16)
#define THREADS 1024            // 16 waves

typedef __attribute__((ext_vector_type(8))) short short8;
typedef __attribute__((ext_vector_type(4))) float float4v;

union U4S8 { uint4 u; short8 s; };

__device__ __forceinline__ unsigned short f2bf(float x) {
    unsigned int u = __float_as_uint(x);
    unsigned int r = (u + 0x7FFFu + ((u >> 16) & 1u)) >> 16;
    return (unsigned short)r;
}
__device__ __forceinline__ float bf2f(unsigned short b) {
    return __uint_as_float(((unsigned int)b) << 16);
}
// order-preserving float<->uint key (exact min via integer atomicMin)
__device__ __forceinline__ unsigned fkey(float f) {
    unsigned u = __float_as_uint(f);
    return (u & 0x80000000u) ? ~u : (u | 0x80000000u);
}
__device__ __forceinline__ float fkeyinv(unsigned k) {
    unsigned u = (k & 0x80000000u) ? (k & 0x7fffffffu) : ~k;
    return __uint_as_float(u);
}

// ---------------- init: z [B,D,T] -> residual [B,T,D], tiled transpose ----------------

__global__ void k_init(const float* __restrict__ z, float* __restrict__ residual,
                       double* lossAcc, unsigned* MelU) {
    __shared__ float tile[32][33];
    int b  = blockIdx.z;
    int d0 = blockIdx.y * 32;
    int t0 = blockIdx.x * 32;
    int tx = threadIdx.x & 31;
    int ty = threadIdx.x >> 5;
    const float* zb = z + (size_t)b * D_ * T_;
    #pragma unroll
    for (int r = 0; r < 32; r += 8)
        tile[ty + r][tx] = zb[(size_t)(d0 + ty + r) * T_ + t0 + tx];
    __syncthreads();
    float* rb = residual + (size_t)b * T_ * D_;
    #pragma unroll
    for (int r = 0; r < 32; r += 8)
        rb[(size_t)(t0 + ty + r) * D_ + d0 + tx] = tile[tx][ty + r];
    if (b == 0 && blockIdx.x == 0 && blockIdx.y == 0 && threadIdx.x == 0) {
        *lossAcc = 0.0;
        #pragma unroll
        for (int i = 0; i < Q_; ++i) MelU[i] = 0u;
    }
}

// ---------------- B-fragment precompute: cb -> bf16 hi/lo in MFMA lane layout ----------
// Layout: Bfrag[((q*64 + ct)*8 + kc)*2*64 + part*64 + lane] : uint4 (8 bf16)
// lane supplies B[k = kc*32 + (lane>>4)*8 + j][n = ct*16 + (lane&15)], j=0..7
// (lo part still written but no longer read by k_stage -- hi-only filter.)

__global__ void k_bfrag(const float* __restrict__ cb, uint4* __restrict__ Bfrag) {
    int gid = blockIdx.x * 256 + threadIdx.x;      // 262144 total
    int q    = gid >> 15;
    int rem  = gid & 32767;
    int ct   = rem >> 9;
    int kc   = (rem >> 6) & 7;
    int lane = rem & 63;
    int cand = ct * 16 + (lane & 15);
    int kb   = kc * 32 + (lane >> 4) * 8;
    const float* e = cb + ((size_t)q * K_ + cand) * D_ + kb;
    float4v u0 = *(const float4v*)(e);
    float4v u1 = *(const float4v*)(e + 4);
    float vv[8] = {u0.x, u0.y, u0.z, u0.w, u1.x, u1.y, u1.z, u1.w};
    unsigned short h[8], l[8];
    #pragma unroll
    for (int j = 0; j < 8; ++j) {
        float v = vv[j];
        h[j] = f2bf(v);
        l[j] = f2bf(v - bf2f(h[j]));
    }
    uint4 hi, lo;
    hi.x = (unsigned)h[0] | ((unsigned)h[1] << 16);
    hi.y = (unsigned)h[2] | ((unsigned)h[3] << 16);
    hi.z = (unsigned)h[4] | ((unsigned)h[5] << 16);
    hi.w = (unsigned)h[6] | ((unsigned)h[7] << 16);
    lo.x = (unsigned)l[0] | ((unsigned)l[1] << 16);
    lo.y = (unsigned)l[2] | ((unsigned)l[3] << 16);
    lo.z = (unsigned)l[4] | ((unsigned)l[5] << 16);
    lo.w = (unsigned)l[6] | ((unsigned)l[7] << 16);
    size_t base = (((size_t)(q * 64 + ct) * 8 + kc) * 2) * 64;
    Bfrag[base + lane]      = hi;
    Bfrag[base + 64 + lane] = lo;
}

// ---------------- S_e + per-stage max bf16-residual norm (DE-CONTENDED) ---------------
// R9's version did 8192 global atomicMax onto 8 words -- an L2 serialization storm
// (~100us, the R8->R9 total regression). Now: per-block LDS max (one block = 16
// entries, all the same q since 16 | 1024) then ONE atomicMax per block (512 total).

__global__ void k_se(const float* __restrict__ cb, float* __restrict__ Se,
                     unsigned* __restrict__ MelU) {
    __shared__ float smax[16];
    int gid = blockIdx.x * 256 + threadIdx.x;      // exactly Q*K*16 threads
    int i  = gid >> 4;
    int ln = gid & 15;
    const float* e = cb + (size_t)i * D_ + ln * 16;
    float4v v0 = *(const float4v*)(e);
    float4v v1 = *(const float4v*)(e + 4);
    float4v v2 = *(const float4v*)(e + 8);
    float4v v3 = *(const float4v*)(e + 12);
    float vv[16] = {v0.x, v0.y, v0.z, v0.w, v1.x, v1.y, v1.z, v1.w,
                    v2.x, v2.y, v2.z, v2.w, v3.x, v3.y, v3.z, v3.w};
    double s = 0.0, s2 = 0.0;
    #pragma unroll
    for (int d = 0; d < 16; ++d) {
        float v = vv[d];
        float a = v * v;
        s += (double)a;
        float el = v - bf2f(f2bf(v));
        s2 += (double)(el * el);
    }
    #pragma unroll
    for (int st = 8; st > 0; st >>= 1) {
        s  += __shfl_xor(s, st);
        s2 += __shfl_xor(s2, st);
    }
    if (ln == 0) {
        Se[i] = (float)s;
        smax[threadIdx.x >> 4] = (float)s2;
    }
    __syncthreads();
    if (threadIdx.x == 0) {
        float m = smax[0];
        #pragma unroll
        for (int t = 1; t < 16; ++t) m = fmaxf(m, smax[t]);
        atomicMax(&MelU[blockIdx.x >> 6], __float_as_uint(m));   // q = blk*16 >> 10
    }
}

// ---------------- per-stage kernel: ROWS=64, 16 waves, HI-ONLY filter ------------------
// Base = R5 (session-best total 781us: ROWS=64 halves per-CU B L2 traffic; 64-VGPR
// clamp spills but nets out ahead). Changes vs R5: (1) hi-only filter -- drop B-lo
// loads + the ah.bl MFMA (2/3 MFMA work, half B stream, -16 prefetch VGPRs -> smaller
// spill set); margin gains 4.04*sqrt(Mel[q])*sqrt(sr) (Cauchy-Schwarz bound on the
// dropped sum r.el term; validated bitwise-identical indices in R9/R11). Exact fp64
// re-rank then yields identical outputs.

__launch_bounds__(THREADS, 1)
__global__ void k_stage(const float* __restrict__ cb,
                        const uint4* __restrict__ Bfrag,
                        const float* __restrict__ Se,
                        const float* __restrict__ Mel,
                        float* __restrict__ residual,
                        float* __restrict__ out,
                        double* __restrict__ lossAcc,
                        int q) {
    __shared__ union {
        uint4 afr[4096];                                  // 64 KB A-frags (filter phase)
        struct { int slist[64][16]; float sdd[64][16];
                 int srow[1024]; int sslot[1024]; } post; // post-filter (16 KB)
        struct { float ovd[1024]; int ovk[1024]; } over;  // overflow fallback
        double lred[16];                                  // loss partials
    } sc;
    __shared__ float seL[1024];                           // 4 KB
    __shared__ float srb[64], margin[64];
    __shared__ unsigned sminI[64];
    __shared__ int   scount[64], sidx[64];
    __shared__ int   nSurv;

    const int tid  = threadIdx.x;
    const int lane = tid & 63;
    const int w    = tid >> 6;          // wave 0..15
    const int quad = lane >> 4;
    const int lc   = lane & 15;
    const int row0 = blockIdx.x * ROWS;
    const int g    = tid >> 8;          // quarter-block 0..3
    const int dt   = tid & 255;

    if (tid < 64) { scount[tid] = 0; sminI[tid] = 0xFFFFFFFFu; }
    if (tid == 64) nSurv = 0;
    seL[tid] = Se[q * K_ + tid];
    const float melq4 = 4.04f * sqrtf(Mel[q]);   // margin term for dropped r.el

    // ---- early B-hi prefetch: steps s=0,1 (kc=0, ct pairs {0,1},{2,3} of this wave) --
    // step s: kc = s>>1, ct = w*4 + (s&1)*2 + {0,1}; buffers alternate on s&1.
    const uint4* __restrict__ Bq = Bfrag + (size_t)q * (64 * 8 * 2 * 64);
    U4S8 bh0[2], bh1[2];
    #pragma unroll
    for (int c = 0; c < 2; ++c) {
        const uint4* p0 = Bq + (((size_t)((w * 4 + c) * 8 + 0)) * 2) * 64 + lane;
        bh0[c].u = p0[0];
        const uint4* p1 = Bq + (((size_t)((w * 4 + 2 + c) * 8 + 0)) * 2) * 64 + lane;
        bh1[c].u = p1[0];
    }

    // ---- FUSED: Sr (fp64) + Sum|r| + A-frag bf16 hi/lo build, single global pass ----
    // pairing order st=8,4,2,1 reproduces the prior association bitwise.
    {
        int row = tid >> 4, seg = tid & 15;       // 64 rows x 16 segs
        int rg = row >> 4, rlo = row & 15;
        int kc = seg >> 1, par = seg & 1;
        const float* rp = residual + (size_t)(row0 + row) * D_ + seg * 16;
        float4v v0 = *(const float4v*)(rp);
        float4v v1 = *(const float4v*)(rp + 4);
        float4v v2 = *(const float4v*)(rp + 8);
        float4v v3 = *(const float4v*)(rp + 12);
        float vv[16] = {v0.x, v0.y, v0.z, v0.w, v1.x, v1.y, v1.z, v1.w,
                        v2.x, v2.y, v2.z, v2.w, v3.x, v3.y, v3.z, v3.w};
        double s = 0.0; float sa = 0.0f;
        #pragma unroll
        for (int i = 0; i < 16; ++i) {
            float v = vv[i];
            s += (double)(v * v);
            sa += fabsf(v);
        }
        #pragma unroll
        for (int st = 8; st > 0; st >>= 1) {
            s  += __shfl_xor(s, st);
            sa += __shfl_xor(sa, st);
        }
        if (seg == 0) {
            float sr = (float)s;
            float sb = sa * 1.001f;
            srb[row]    = sr;
            margin[row] = 9.6e-7f * sr + 4.0e-7f * sb + 2.0e-4f
                        + melq4 * sqrtf(sr);
        }
        // afr slot = blk*64 + (ln ^ kc); XOR spreads write banks; reads stay a
        // permutation of a contiguous 64-block.
        #pragma unroll
        for (int h = 0; h < 2; ++h) {
            unsigned short hh[8], ll[8];
            #pragma unroll
            for (int j = 0; j < 8; ++j) {
                float v = vv[h * 8 + j];
                hh[j] = f2bf(v);
                ll[j] = f2bf(v - bf2f(hh[j]));
            }
            uint4 hiW, loW;
            hiW.x = (unsigned)hh[0] | ((unsigned)hh[1] << 16);
            hiW.y = (unsigned)hh[2] | ((unsigned)hh[3] << 16);
            hiW.z = (unsigned)hh[4] | ((unsigned)hh[5] << 16);
            hiW.w = (unsigned)hh[6] | ((unsigned)hh[7] << 16);
            loW.x = (unsigned)ll[0] | ((unsigned)ll[1] << 16);
            loW.y = (unsigned)ll[2] | ((unsigned)ll[3] << 16);
            loW.z = (unsigned)ll[4] | ((unsigned)ll[5] << 16);
            loW.w = (unsigned)ll[6] | ((unsigned)ll[7] << 16);
            int ln = (par * 2 + h) * 16 + rlo;
            int sl = ln ^ kc;
            sc.afr[((rg * 8 + kc) * 2 + 0) * 64 + sl] = hiW;
            sc.afr[((rg * 8 + kc) * 2 + 1) * 64 + sl] = loW;
        }
    }
    __syncthreads();

    // ---- MFMA filter: wave w covers ct = w*4..w*4+3, all 4 row-groups ----
    // 16 steps s (kc = s>>1, ct-pair = s&1); rolling depth-2 B-hi prefetch of step s+2
    // (tail clamped; harmless reload). 2 MFMAs per acc: ah.bh + al.bh.
    float4v accA[16];                   // [c*4 + rg]
    #pragma unroll
    for (int i = 0; i < 16; ++i) accA[i] = (float4v){0.f, 0.f, 0.f, 0.f};

    for (int s = 0; s < 16; ++s) {
        int kc = s >> 1;
        int cb0 = (s & 1) * 2;          // ct offset of this pair
        U4S8 bh[2];
        if ((s & 1) == 0) { bh[0] = bh0[0]; bh[1] = bh0[1]; }
        else              { bh[0] = bh1[0]; bh[1] = bh1[1]; }
        // prefetch step s+2 (same parity buffer, hi only), clamp tail
        {
            int ps  = (s + 2 > 15) ? 15 : (s + 2);
            int pkc = ps >> 1;
            int pc0 = (ps & 1) * 2;
            #pragma unroll
            for (int c = 0; c < 2; ++c) {
                const uint4* p = Bq + (((size_t)((w * 4 + pc0 + c) * 8 + pkc)) * 2) * 64 + lane;
                if ((s & 1) == 0) bh0[c].u = p[0];
                else              bh1[c].u = p[0];
            }
        }
        #pragma unroll
        for (int rg = 0; rg < 4; ++rg) {
            U4S8 ah, al;
            ah.u = sc.afr[((rg * 8 + kc) * 2 + 0) * 64 + (lane ^ kc)];
            al.u = sc.afr[((rg * 8 + kc) * 2 + 1) * 64 + (lane ^ kc)];
            #pragma unroll
            for (int c = 0; c < 2; ++c) {
                float4v a = accA[(cb0 + c) * 4 + rg];
                a = __builtin_amdgcn_mfma_f32_16x16x32_bf16(ah.s, bh[c].s, a, 0, 0, 0);
                a = __builtin_amdgcn_mfma_f32_16x16x32_bf16(al.s, bh[c].s, a, 0, 0, 0);
                accA[(cb0 + c) * 4 + rg] = a;
            }
        }
    }

    // ---- per-lane mins; D layout: row = rg*16 + quad*4 + reg, col = lc ----
    float sr16[16];
    #pragma unroll
    for (int rr = 0; rr < 16; ++rr)
        sr16[rr] = srb[(rr >> 2) * 16 + quad * 4 + (rr & 3)];

    float mn[16];
    #pragma unroll
    for (int rr = 0; rr < 16; ++rr) mn[rr] = 3.4e38f;
    #pragma unroll
    for (int c = 0; c < 4; ++c) {
        int cand = (w * 4 + c) * 16 + lc;
        float se = seL[cand];
        #pragma unroll
        for (int rr = 0; rr < 16; ++rr) {
            float dd = (sr16[rr] + se) - 2.0f * accA[c * 4 + (rr >> 2)][rr & 3];
            mn[rr] = fminf(mn[rr], dd);
        }
    }
    #pragma unroll
    for (int rr = 0; rr < 16; ++rr) {
        float v = mn[rr];
        v = fminf(v, __shfl_xor(v, 1));
        v = fminf(v, __shfl_xor(v, 2));
        v = fminf(v, __shfl_xor(v, 4));
        v = fminf(v, __shfl_xor(v, 8));
        if (lc == 0)
            atomicMin(&sminI[(rr >> 2) * 16 + quad * 4 + (rr & 3)], fkey(v));
    }
    __syncthreads();

    // ---- survivor collection (thr = exact block min + margin) ----
    #pragma unroll
    for (int c = 0; c < 4; ++c) {
        int cand = (w * 4 + c) * 16 + lc;
        float se = seL[cand];
        #pragma unroll
        for (int rr = 0; rr < 16; ++rr) {
            int row = (rr >> 2) * 16 + quad * 4 + (rr & 3);
            float dd = (sr16[rr] + se) - 2.0f * accA[c * 4 + (rr >> 2)][rr & 3];
            float thr = fkeyinv(sminI[row]) + margin[row];
            if (dd <= thr) {
                int p = atomicAdd(&scount[row], 1);
                if (p < 16) sc.post.slist[row][p] = cand;
            }
        }
    }
    __syncthreads();

    // ---- compact survivors block-wide; cnt==1 rows resolved immediately ----
    if (tid < 64) {
        int cnt = scount[tid];
        if (cnt == 1) {
            sidx[tid] = sc.post.slist[tid][0];
        } else if (cnt >= 2 && cnt <= 16) {
            int base = atomicAdd(&nSurv, cnt);
            for (int s2 = 0; s2 < cnt; ++s2) {
                sc.post.srow[base + s2]  = tid;
                sc.post.sslot[base + s2] = s2;
            }
        }
    }
    __syncthreads();

    // ---- exact fp64 re-rank: 16 lanes per survivor, vectorized loads ----
    {
        int nS  = nSurv;
        int grp = tid >> 4, ln = tid & 15;
        for (int j = grp; j < nS; j += 64) {
            int row  = sc.post.srow[j];
            int slot = sc.post.sslot[j];
            int k    = sc.post.slist[row][slot];
            const float* Ek = cb + ((size_t)q * K_ + k) * D_ + ln * 16;
            const float* Rk = residual + (size_t)(row0 + row) * D_ + ln * 16;
            float4v e0 = *(const float4v*)(Ek);
            float4v e1 = *(const float4v*)(Ek + 4);
            float4v e2 = *(const float4v*)(Ek + 8);
            float4v e3 = *(const float4v*)(Ek + 12);
            float4v r0 = *(const float4v*)(Rk);
            float4v r1 = *(const float4v*)(Rk + 4);
            float4v r2 = *(const float4v*)(Rk + 8);
            float4v r3 = *(const float4v*)(Rk + 12);
            float ev[16] = {e0.x, e0.y, e0.z, e0.w, e1.x, e1.y, e1.z, e1.w,
                            e2.x, e2.y, e2.z, e2.w, e3.x, e3.y, e3.z, e3.w};
            float rv2[16] = {r0.x, r0.y, r0.z, r0.w, r1.x, r1.y, r1.z, r1.w,
                             r2.x, r2.y, r2.z, r2.w, r3.x, r3.y, r3.z, r3.w};
            double a0 = 0.0, a1 = 0.0;
            #pragma unroll
            for (int d = 0; d < 16; d += 2) {
                a0 = fma((double)ev[d],     (double)rv2[d],     a0);
                a1 = fma((double)ev[d + 1], (double)rv2[d + 1], a1);
            }
            double ssum = a0 + a1;
            #pragma unroll
            for (int st = 8; st > 0; st >>= 1) ssum += __shfl_xor(ssum, st);
            if (ln == 0) {
                float dotf = (float)ssum;
                float V = srb[row] + seL[k];
                sc.post.sdd[row][slot] = V - 2.0f * dotf;
            }
        }
    }
    __syncthreads();
    if (tid < 64) {
        int cnt = scount[tid];
        if (cnt >= 2 && cnt <= 16) {
            float bd = 3.4e38f; int bk = 0x7fffffff;
            for (int s2 = 0; s2 < cnt; ++s2) {
                float dv = sc.post.sdd[tid][s2]; int kv = sc.post.slist[tid][s2];
                if (dv < bd || (dv == bd && kv < bk)) { bd = dv; bk = kv; }
            }
            sidx[tid] = bk;
        }
    }
    __syncthreads();

    // ---- overflow fallback (>16 survivors; exact, block-wide, rare) ----
    for (int row = 0; row < ROWS; ++row) {
        int cnt = scount[row];
        if (cnt <= 16) continue;
        const float* Rr = residual + (size_t)(row0 + row) * D_;
        int k = tid;                    // one candidate per thread (K_ == THREADS)
        const float* Ek = cb + ((size_t)q * K_ + k) * D_;
        double a0 = 0.0, a1 = 0.0;
        for (int d = 0; d < D_; d += 2) {
            a0 = fma((double)Ek[d],     (double)Rr[d],     a0);
            a1 = fma((double)Ek[d + 1], (double)Rr[d + 1], a1);
        }
        float bd = (srb[row] + seL[k]) - 2.0f * (float)(a0 + a1);
        sc.over.ovd[tid] = bd; sc.over.ovk[tid] = k;
        __syncthreads();
        for (int st = 512; st > 0; st >>= 1) {
            if (tid < st) {
                float od = sc.over.ovd[tid + st]; int ok = sc.over.ovk[tid + st];
                if (od < sc.over.ovd[tid] ||
                    (od == sc.over.ovd[tid] && ok < sc.over.ovk[tid])) {
                    sc.over.ovd[tid] = od; sc.over.ovk[tid] = ok;
                }
            }
            __syncthreads();
        }
        if (tid == 0) sidx[row] = sc.over.ovk[0];
        __syncthreads();
    }

    // ---- epilogue: exact fp32 STE residual update (bitwise as prior rounds) ----
    const float* Eq = cb + (size_t)q * K_ * D_;
    double lsum = 0.0;
    #pragma unroll
    for (int jj = 0; jj < 16; ++jj) {
        int row = g * 16 + jj;
        int idx = sidx[row];
        size_t roff = (size_t)(row0 + row) * D_ + dt;
        float rv   = residual[roff];
        float zq   = Eq[(size_t)idx * D_ + dt];
        float t1   = zq - rv;
        float zqst = rv + t1;
        residual[roff] = rv - zqst;
        lsum += (double)t1 * (double)t1;
    }
    if (tid < 64) out[IDX_OFF + q * BT_ + row0 + tid] = (float)sidx[tid];

    // ---- loss: wave shuffle reduce + 16 partials ----
    #pragma unroll
    for (int st = 32; st > 0; st >>= 1) lsum += __shfl_xor(lsum, st);
    __syncthreads();                     // union reuse: post/over dead
    if (lane == 0) sc.lred[w] = lsum;
    __syncthreads();
    if (tid == 0) {
        double t = 0.0;
        #pragma unroll
        for (int i = 0; i < 16; ++i) t += sc.lred[i];
        atomicAdd(lossAcc, t);
    }
}

// ---------------- emit: out[b,d,t] = z[b,d,t] - r_final[b,t,d] ----------------

__global__ void k_emit(const float* __restrict__ z, const float* __restrict__ residual,
                       float* __restrict__ out) {
    __shared__ float tile[32][33];
    int b  = blockIdx.z;
    int t0 = blockIdx.y * 32;
    int d0 = blockIdx.x * 32;
    int tx = threadIdx.x & 31;
    int ty = threadIdx.x >> 5;
    const float* rb = residual + (size_t)b * T_ * D_;
    #pragma unroll
    for (int r = 0; r < 32; r += 8)
        tile[ty + r][tx] = rb[(size_t)(t0 + ty + r) * D_ + d0 + tx];
    __syncthreads();
    const float* zb = z + (size_t)b * D_ * T_;
    float* ob = out + (size_t)b * D_ * T_;
    #pragma unroll
    for (int r = 0; r < 32; r += 8) {
        size_t off = (size_t)(d0 + ty + r) * T_ + t0 + tx;
        ob[off] = zb[off] - tile[tx][ty + r];
    }
}

__global__ void k_final(const double* lossAcc, float* out) {
    if (threadIdx.x == 0 && blockIdx.x == 0) {
        double m = *lossAcc / (double)N_;
        out[LOSS_OFF] = (float)(1.25 * m);
    }
}

// ---------------- launcher ----------------

extern "C" void kernel_launch(void* const* d_in, const int* in_sizes, int n_in,
                              void* d_out, int out_size, void* d_ws, size_t ws_size,
                              hipStream_t stream) {
    const float* z  = (const float*)d_in[0];
    const float* cb = (const float*)d_in[1];
    float* out = (float*)d_out;

    // ws layout: residual f32[N_] (32MB) | Bfrag uint4 (8MB) | Se f32[Q*K]
    //            | loss double | MelU u32[Q]
    float*  residual = (float*)d_ws;
    uint4*  Bfrag    = (uint4*)((char*)d_ws + (size_t)N_ * 4);
    float*  Se       = (float*)((char*)d_ws + (size_t)N_ * 4 + (size_t)8 * 1024 * 1024);
    double* lossAcc  = (double*)((char*)d_ws + (size_t)N_ * 4 + (size_t)8 * 1024 * 1024
                                 + (size_t)Q_ * K_ * 4);
    unsigned* MelU   = (unsigned*)((char*)lossAcc + 8);

    hipLaunchKernelGGL(k_init, dim3(T_ / 32, D_ / 32, B_), dim3(256), 0, stream,
                       z, residual, lossAcc, MelU);
    hipLaunchKernelGGL(k_bfrag, dim3(1024), dim3(256), 0, stream, cb, Bfrag);
    hipLaunchKernelGGL(k_se, dim3(Q_ * K_ * 16 / 256), dim3(256), 0, stream,
                       cb, Se, MelU);
    for (int q = 0; q < Q_; ++q) {
        hipLaunchKernelGGL(k_stage, dim3(BT_ / ROWS), dim3(THREADS), 0, stream,
                           cb, Bfrag, Se, (const float*)MelU, residual, out, lossAcc, q);
    }
    hipLaunchKernelGGL(k_emit, dim3(D_ / 32, T_ / 32, B_), dim3(256), 0, stream,
                       z, residual, out);
    hipLaunchKernelGGL(k_final, dim3(1), dim3(256), 0, stream, lossAcc, out);
}